// Round 15
// baseline (9429.810 us; speedup 1.0000x reference)
//
#include <hip/hip_runtime.h>
#include <math.h>

#define LAYERS 8
#define C 384
#define NH 8
#define NE 4
#define TD 256
#define NV 256
#define WIN 64
#define MM 56
#define HD 48
#define BB 64
#define TT 256
#define NT (BB*TT)
#define N3C 1152
#define FF 1536
#define KV 312
#define ACH 104              // attention KV chunk rows (3*104 = 312)
#define FCH 384              // MoE FF chunk width (768 overflowed rb — r14 crash)
#define SCALE_QK 0.14433756729740643f

typedef _Float16 f16;
typedef __attribute__((ext_vector_type(8))) _Float16 f16x8;
typedef __attribute__((ext_vector_type(4))) _Float16 f16x4;
typedef __attribute__((ext_vector_type(4))) float f32x4;

static __device__ __forceinline__ float wsum(float v){
#pragma unroll
  for(int o=32;o;o>>=1) v += __shfl_xor(v,o);
  return v;
}

// ---------------- embed ----------------
__global__ void k_embed(const int* __restrict__ tokens, const float* __restrict__ tok_emb,
                        const float* __restrict__ pos_emb, float* __restrict__ x){
  int idx = blockIdx.x*256 + threadIdx.x;
  if (idx >= NT*C) return;
  int t = idx / C, c = idx - t*C;
  x[idx] = tok_emb[tokens[t]*C + c] + pos_emb[(t % TT)*C + c];
}

// ---------------- layernorm -> f16 hi/lo pair ----------------
__global__ void k_ln(const float* __restrict__ in, const float* __restrict__ w,
                     const float* __restrict__ b,
                     f16* __restrict__ oh, f16* __restrict__ ol){
  int row = blockIdx.x*4 + (threadIdx.x>>6);
  int lane = threadIdx.x & 63;
  const float* xr = in + (size_t)row*C;
  float v[6]; float s = 0.f;
#pragma unroll
  for(int i=0;i<6;i++){ v[i]=xr[lane+64*i]; s+=v[i]; }
  s = wsum(s);
  float mu = s*(1.f/C);
  float q=0.f;
#pragma unroll
  for(int i=0;i<6;i++){ float d=v[i]-mu; q+=d*d; }
  q = wsum(q);
  float inv = rsqrtf(q*(1.f/C)+1e-5f);
#pragma unroll
  for(int i=0;i<6;i++){
    int c = lane+64*i;
    float o = (v[i]-mu)*inv*w[c]+b[c];
    size_t oi = (size_t)row*C + c;
    f16 hh = (f16)o;
    oh[oi] = hh;
    ol[oi] = (f16)(o - (float)hh);
  }
}

// ---------------- weight split+transpose: W[K][N] fp32 -> WhT/WlT [N][K] f16 ----------------
__global__ __launch_bounds__(256) void k_wsplit(const float* __restrict__ W,
    f16* __restrict__ WhT, f16* __restrict__ WlT, int Kn, int Nn){
  __shared__ float s[32][33];
  const size_t ofs = (size_t)blockIdx.z*Kn*Nn;
  const float* Wb = W + ofs;
  f16* Th = WhT + ofs;
  f16* Tl = WlT + ofs;
  int k0 = (int)blockIdx.x<<5, n0 = (int)blockIdx.y<<5;
  int t = threadIdx.x;
  int r = t>>3, c4 = (t&7)<<2;
  float4 v = *(const float4*)(Wb + (size_t)(k0+r)*Nn + n0 + c4);
  s[r][c4+0]=v.x; s[r][c4+1]=v.y; s[r][c4+2]=v.z; s[r][c4+3]=v.w;
  __syncthreads();
  f16x4 hv, lv;
#pragma unroll
  for(int i=0;i<4;i++){
    float f = s[c4+i][r];
    f16 hh = (f16)f;
    hv[i] = hh;
    lv[i] = (f16)(f - (float)hh);
  }
  *(f16x4*)(Th + (size_t)(n0+r)*Kn + k0 + c4) = hv;
  *(f16x4*)(Tl + (size_t)(n0+r)*Kn + k0 + c4) = lv;
}

// ---------------- pair MFMA GEMM: fp16-split 3-pass, 128x128 tile, 4 waves ----------------
// D = A*B, A/B split hi+lo f16: acc += Ah*Bh + Ah*Bl + Al*Bh  (rel err ~2^-22).
// EPI 0: Of = val (+bias if bz)          (qkv, head, e2 first chunk)
// EPI 1: Of += val (+bias if bz)         (th2, e2 later chunks)
// EPI 2: gelu(val+bias) -> pair Oh/Ol    (e1)
// EPI 3: nv = Of+val+bias; Of=nv; pair(nv) -> Oh/Ol   (proj: x-accum + x-pair)
// EPI 4: tanh(val+bias) -> pair Oh/Ol    (th1)
// MOE: blockIdx.z = expert (cnt/eb); GATHER: A rows via ridx.
template<int EPI, bool MOE, bool GATHER>
__global__ __launch_bounds__(256) void k_mfma(
    const f16* __restrict__ Ah16, const f16* __restrict__ Al16,
    const f16* __restrict__ WhT, const f16* __restrict__ WlT,
    const float* __restrict__ bias,
    const int* __restrict__ ridx, const int* __restrict__ cnt,
    size_t sW, size_t sB,
    f16* __restrict__ Oh, f16* __restrict__ Ol, float* __restrict__ Of,
    int Kn, int ldA, int ldW, int ldC)
{
  const int z = MOE ? (int)blockIdx.z : 0;
  int Mn = NT, eb = 0;
  if (MOE){
    Mn = 0;
#pragma unroll
    for(int i=0;i<NE;i++){ int ci = cnt[i]; if (i<z) eb += ci; if (i==z) Mn = ci; }
  }
  const int bm = (int)blockIdx.y<<7, bn = (int)blockIdx.x<<7;
  if (bm >= Mn) return;
  const f16* Wh = WhT + (MOE ? (size_t)z*sW : 0);
  const f16* Wl = WlT + (MOE ? (size_t)z*sW : 0);
  const float* bz = bias ? (bias + (MOE ? (size_t)z*sB : 0)) : nullptr;

  __shared__ f16 AhS[128][40];
  __shared__ f16 AlS[128][40];
  __shared__ f16 BhS[128][40];
  __shared__ f16 BlS[128][40];

  const int tid = threadIdx.x;
  const int lane = tid & 63, wave = tid >> 6;
  const int srow = tid >> 1, sh2 = tid & 1;
  int r0 = bm + srow; if (r0 >= Mn) r0 = Mn - 1;
  const int agr = GATHER ? ridx[(size_t)z*NT + r0] : (eb + r0);
  const f16* As_h = Ah16 + (size_t)agr*ldA + (sh2<<4);
  const f16* As_l = Al16 + (size_t)agr*ldA + (sh2<<4);
  const f16* Bs_h = Wh + (size_t)(bn + srow)*ldW + (sh2<<4);
  const f16* Bs_l = Wl + (size_t)(bn + srow)*ldW + (sh2<<4);

  const int wr = (wave>>1)<<6, wc = (wave&1)<<6;
  const int l15 = lane & 15, koff = (lane>>4)<<3;
  f32x4 acc[4][4] = {};
  const int T = Kn >> 5;
  for (int t=0; t<T; t++){
    const int k0 = t<<5;
    __syncthreads();                       // WAR: previous frag reads complete
    {
      f16x8 a0 = *(const f16x8*)(As_h + k0);
      f16x8 a1 = *(const f16x8*)(As_h + k0 + 8);
      f16x8 a2 = *(const f16x8*)(As_l + k0);
      f16x8 a3 = *(const f16x8*)(As_l + k0 + 8);
      f16x8 b0 = *(const f16x8*)(Bs_h + k0);
      f16x8 b1 = *(const f16x8*)(Bs_h + k0 + 8);
      f16x8 b2 = *(const f16x8*)(Bs_l + k0);
      f16x8 b3 = *(const f16x8*)(Bs_l + k0 + 8);
      *(f16x8*)&AhS[srow][sh2<<4]     = a0;
      *(f16x8*)&AhS[srow][(sh2<<4)+8] = a1;
      *(f16x8*)&AlS[srow][sh2<<4]     = a2;
      *(f16x8*)&AlS[srow][(sh2<<4)+8] = a3;
      *(f16x8*)&BhS[srow][sh2<<4]     = b0;
      *(f16x8*)&BhS[srow][(sh2<<4)+8] = b1;
      *(f16x8*)&BlS[srow][sh2<<4]     = b2;
      *(f16x8*)&BlS[srow][(sh2<<4)+8] = b3;
    }
    __syncthreads();                       // staged tile visible
    f16x8 fah[4], fal[4], fbh[4], fbl[4];
#pragma unroll
    for(int m=0;m<4;m++){
      fah[m] = *(const f16x8*)&AhS[wr + (m<<4) + l15][koff];
      fal[m] = *(const f16x8*)&AlS[wr + (m<<4) + l15][koff];
    }
#pragma unroll
    for(int n=0;n<4;n++){
      fbh[n] = *(const f16x8*)&BhS[wc + (n<<4) + l15][koff];
      fbl[n] = *(const f16x8*)&BlS[wc + (n<<4) + l15][koff];
    }
#pragma unroll
    for(int m=0;m<4;m++)
#pragma unroll
      for(int n=0;n<4;n++){
        acc[m][n] = __builtin_amdgcn_mfma_f32_16x16x32_f16(fah[m], fbh[n], acc[m][n], 0,0,0);
        acc[m][n] = __builtin_amdgcn_mfma_f32_16x16x32_f16(fah[m], fbl[n], acc[m][n], 0,0,0);
        acc[m][n] = __builtin_amdgcn_mfma_f32_16x16x32_f16(fal[m], fbh[n], acc[m][n], 0,0,0);
      }
  }
  // epilogue: C/D layout col=lane&15, row=(lane>>4)*4+reg
  const int r4 = (lane>>4)<<2;
#pragma unroll
  for(int m=0;m<4;m++){
#pragma unroll
    for(int n=0;n<4;n++){
      const int col = bn + wc + (n<<4) + l15;
#pragma unroll
      for(int rr=0;rr<4;rr++){
        const int row = bm + wr + (m<<4) + r4 + rr;
        if (row < Mn){
          float val = acc[m][n][rr];
          const size_t o = (size_t)(eb+row)*ldC + col;
          if (EPI==2 || EPI==4){
            val += bz[col];
            val = (EPI==2) ? 0.5f*val*(1.0f+erff(val*0.70710678118654752f)) : tanhf(val);
            f16 hv = (f16)val;
            Oh[o] = hv;
            Ol[o] = (f16)(val - (float)hv);
          } else if (EPI==3){
            val += bz[col];
            float nv = Of[o] + val;
            Of[o] = nv;
            f16 hv = (f16)nv;
            Oh[o] = hv;
            Ol[o] = (f16)(nv - (float)hv);
          } else if (EPI==1){
            if (bz) val += bz[col];
            Of[o] += val;
          } else {
            if (bz) val += bz[col];
            Of[o] = val;
          }
        }
      }
    }
  }
}

// ---------------- attention: chunked flash, lane-per-query, y -> f16 pair ----------------
// KV staged in 3 chunks of ACH=104 rows (LDS 41.6 KB -> 3 blocks/CU). Processing
// order stays globally ascending j => bitwise-identical to the unchunked version.
__global__ __launch_bounds__(256) void k_attn(const float* __restrict__ qkv,
    const float* __restrict__ mem, const float* __restrict__ gate,
    f16* __restrict__ yh, f16* __restrict__ yl){
  __shared__ float ks[ACH*50];
  __shared__ float vs[ACH*50];
  const int b = blockIdx.x >> 3, hh = blockIdx.x & 7;
  const int tid = threadIdx.x;
  const int i = tid;
  const float* qrow = qkv + (size_t)(b*TT+i)*N3C + hh*HD;
  float q[HD];
#pragma unroll
  for(int d2=0; d2<24; d2++){
    float2 qv = *(const float2*)(qrow + d2*2);
    q[d2*2] = qv.x; q[d2*2+1] = qv.y;
  }
  float m = -1e30f, l = 0.f;
  float acc[HD];
#pragma unroll
  for(int d=0;d<HD;d++) acc[d]=0.f;
  const int lo = (i > WIN) ? (i - WIN) : 0;

#define ATT_STEP(JROW) {                                            \
    const float* kr = ks + (JROW)*50;                               \
    float dot = 0.f;                                                \
    _Pragma("unroll")                                               \
    for(int d2=0; d2<24; d2++){                                     \
      float2 kv2 = *(const float2*)(kr + d2*2);                     \
      dot += q[d2*2]*kv2.x + q[d2*2+1]*kv2.y;                       \
    }                                                               \
    float s = dot*SCALE_QK;                                         \
    if (s > m + 8.f){                                               \
      float f_ = __expf(m - s);                                     \
      l *= f_;                                                      \
      _Pragma("unroll")                                             \
      for(int d=0; d<HD; d++) acc[d] *= f_;                         \
      m = s;                                                        \
    }                                                               \
    float pch = __expf(s - m);                                      \
    l += pch;                                                       \
    const float* vr = vs + (JROW)*50;                               \
    _Pragma("unroll")                                               \
    for(int d2=0; d2<24; d2++){                                     \
      float2 vv2 = *(const float2*)(vr + d2*2);                     \
      acc[d2*2]   += pch*vv2.x;                                     \
      acc[d2*2+1] += pch*vv2.y;                                     \
    }                                                               \
  }

  for (int ch=0; ch<3; ++ch){
    const int j0 = ch*ACH;
    if (ch) __syncthreads();             // WAR before restaging
    for(int idx=tid; idx<ACH*24; idx+=256){
      int jr = idx/24, f = (idx - jr*24)*2;
      int j = j0 + jr;
      float2 kvv, vvv;
      if (j < MM){
        kvv = *(const float2*)(mem + j*C + hh*HD + f);
        vvv = kvv;
      } else {
        const float* row = qkv + (size_t)(b*TT + j - MM)*N3C + hh*HD + f;
        kvv = *(const float2*)(row + C);
        vvv = *(const float2*)(row + 2*C);
      }
      *(float2*)(ks + jr*50 + f) = kvv;
      *(float2*)(vs + jr*50 + f) = vvv;
    }
    __syncthreads();
    const int mend = (MM < j0+ACH) ? MM : (j0+ACH);
    for (int j=j0; j<mend; ++j) ATT_STEP(j-j0)
    const int slo = (MM+lo > j0) ? (MM+lo) : j0;
    const int shi = (MM+i+1 < j0+ACH) ? (MM+i+1) : (j0+ACH);
    for (int j=slo; j<shi; ++j) ATT_STEP(j-j0)
  }
#undef ATT_STEP

  const float inv = 1.f/l;
  const float* g = gate + hh*HD;
  const size_t base = (size_t)(b*TT+i)*C + hh*HD;
#pragma unroll
  for(int d=0;d<HD;d++){
    float o = acc[d]*inv*g[d];
    f16 hv = (f16)o;
    yh[base+d] = hv;
    yl[base+d] = (f16)(o - (float)hv);
  }
}

// ---------------- router (reads h2 pair; hi+lo reconstruct, err ~2^-22) ----------------
__global__ void k_gate(const f16* __restrict__ hh2, const f16* __restrict__ hl2,
                       const float* __restrict__ gw,
                       const float* __restrict__ gb, float* __restrict__ wout){
  int row = blockIdx.x*4 + (threadIdx.x>>6);
  int lane = threadIdx.x & 63;
  const f16* hr = hh2 + (size_t)row*C;
  const f16* lr = hl2 + (size_t)row*C;
  float a0=0,a1=0,a2=0,a3=0;
  for(int c=lane;c<C;c+=64){
    float hv = (float)hr[c] + (float)lr[c];
    const float* g = gw + c*NE;
    a0+=hv*g[0]; a1+=hv*g[1]; a2+=hv*g[2]; a3+=hv*g[3];
  }
  a0=wsum(a0); a1=wsum(a1); a2=wsum(a2); a3=wsum(a3);
  if (lane==0){
    float p[4]={a0+gb[0],a1+gb[1],a2+gb[2],a3+gb[3]};
    float m = fmaxf(fmaxf(p[0],p[1]),fmaxf(p[2],p[3]));
    float s=0.f;
#pragma unroll
    for(int e=0;e<4;e++){ p[e]=expf(p[e]-m); s+=p[e]; }
#pragma unroll
    for(int e=0;e<4;e++) p[e] /= s;
    int i1=0;
    for(int e=1;e<4;e++) if(p[e]>p[i1]) i1=e;
    int i2=-1;
    for(int e=0;e<4;e++){ if(e==i1) continue; if(i2<0 || p[e]>p[i2]) i2=e; }
    float invs = 1.f/(p[i1]+p[i2]+1e-9f);
    float wv[4]={0.f,0.f,0.f,0.f};
    wv[i1]=p[i1]*invs; wv[i2]=p[i2]*invs;
    float* o = wout + (size_t)row*NE;
    o[0]=wv[0]; o[1]=wv[1]; o[2]=wv[2]; o[3]=wv[3];
  }
}

// ---------------- per-expert compaction + inverse map ----------------
__global__ __launch_bounds__(256) void k_compact(const float* __restrict__ wbuf,
    int* __restrict__ ridx, int* __restrict__ posmap, int* __restrict__ cnt){
  int e = blockIdx.x;
  int tid = threadIdx.x;
  int wave = tid>>6, lane = tid&63;
  __shared__ int wsum_s[4];
  __shared__ int base_s;
  if (tid==0) base_s = 0;
  __syncthreads();
  for(int t0=0; t0<NT; t0+=256){
    int t = t0 + tid;
    bool f = wbuf[(size_t)t*NE + e] > 0.f;
    unsigned long long bal = __ballot(f);
    int pre = __popcll(bal & ((1ull<<lane)-1ull));
    if (lane==0) wsum_s[wave] = __popcll(bal);
    __syncthreads();
    int off = 0;
#pragma unroll
    for(int w2=0;w2<4;w2++) if (w2 < wave) off += wsum_s[w2];
    int tot = wsum_s[0]+wsum_s[1]+wsum_s[2]+wsum_s[3];
    int b0 = base_s;
    int pos = b0 + off + pre;
    if (f) ridx[(size_t)e*NT + pos] = t;
    posmap[(size_t)t*NE + e] = f ? pos : -1;
    __syncthreads();
    if (tid==0) base_s = b0 + tot;
    __syncthreads();
  }
  if (tid==0) cnt[e] = base_s;
}

// ---------------- MoE gather ----------------
__global__ __launch_bounds__(256) void k_moe_gather(const float* __restrict__ ye,
    const float* __restrict__ wbuf, const int* __restrict__ posmap,
    const int* __restrict__ cnt, float* __restrict__ x){
  int idx = blockIdx.x*256 + threadIdx.x;
  if (idx >= NT*(C/4)) return;
  int eb[NE]; int s=0;
#pragma unroll
  for(int e=0;e<NE;e++){ eb[e]=s; s+=cnt[e]; }
  int t = idx/(C/4), c4 = (idx - t*(C/4))*4;
  float4 acc = *(const float4*)(x + (size_t)t*C + c4);
#pragma unroll
  for(int e=0;e<NE;e++){
    int p = posmap[(size_t)t*NE + e];
    if (p >= 0){
      float w = wbuf[(size_t)t*NE + e];
      float4 yv = *(const float4*)(ye + (size_t)(eb[e]+p)*C + c4);
      acc.x += w*yv.x; acc.y += w*yv.y; acc.z += w*yv.z; acc.w += w*yv.w;
    }
  }
  *(float4*)(x + (size_t)t*C + c4) = acc;
}

extern "C" void kernel_launch(void* const* d_in, const int* in_sizes, int n_in,
                              void* d_out, int out_size, void* d_ws, size_t ws_size,
                              hipStream_t stream){
  (void)in_sizes; (void)n_in; (void)out_size; (void)ws_size;
  const int*   tokens  = (const int*)d_in[0];
  const float* tok_emb = (const float*)d_in[1];
  const float* pos_emb = (const float*)d_in[2];
  const float* mem     = (const float*)d_in[3];
  const float* ln1_w   = (const float*)d_in[4];
  const float* ln1_b   = (const float*)d_in[5];
  const float* qkv_w   = (const float*)d_in[6];
  const float* qkv_b   = (const float*)d_in[7];
  const float* proj_w  = (const float*)d_in[8];
  const float* proj_b  = (const float*)d_in[9];
  const float* attn_g  = (const float*)d_in[10];
  const float* th1_w   = (const float*)d_in[11];
  const float* th1_b   = (const float*)d_in[12];
  const float* th2_w   = (const float*)d_in[13];
  const float* th2_b   = (const float*)d_in[14];
  const float* ln2_w   = (const float*)d_in[15];
  const float* ln2_b   = (const float*)d_in[16];
  const float* gate_w  = (const float*)d_in[17];
  const float* gate_b  = (const float*)d_in[18];
  const float* e1_w    = (const float*)d_in[19];
  const float* e1_b    = (const float*)d_in[20];
  const float* e2_w    = (const float*)d_in[21];
  const float* e2_b    = (const float*)d_in[22];
  const float* lnf_w   = (const float*)d_in[23];
  const float* lnf_b   = (const float*)d_in[24];
  const float* head_w  = (const float*)d_in[25];
  const float* head_b  = (const float*)d_in[26];
  float* out = (float*)d_out;

  char* p = (char*)d_ws;
  float* x   = (float*)p; p += (size_t)NT*C*4;          // residual fp32
  f16* pAh = (f16*)p;                                    // shared pair plane:
  f16* pAl = pAh + (size_t)NT*C;                         //  xp (proj->th1) / h2p (ln2->e1) / lnf pair
  p += (size_t)NT*C*4;
  char* rb = p; p += (size_t)NT*N3C*4 + (size_t)2*NT*TD*4;   // 109.05 MB region
  float* qkvb = (float*)rb;                              // [0, 75.5MB)
  char* shreg = rb + (size_t)NT*N3C*4;                   // [75.5, 109MB)
  f16* h1h = (f16*)shreg; f16* h1l = h1h + (size_t)NT*C; // ln1 pair (dead after qkv)
  f16* yh  = h1h;         f16* yl  = h1l;                // attn pair (dead after proj)
  f16* t1h = h1h;         f16* t1l = t1h + (size_t)NT*TD;// th1 pair (dead after th2)
  // MoE-phase aliases in rb (qkvb + shreg dead then). FCH=384:
  // heh [0,25.17), hel [25.17,50.33), ye [50.33,100.66) MB — fits 109.05.
  f16* heh = (f16*)rb;
  f16* hel = heh + (size_t)2*NT*FCH;
  float* ye = (float*)(rb + (size_t)2*2*NT*FCH*2);
  float* wbuf = (float*)p; p += (size_t)NT*NE*4;
  int*   ridx = (int*)p;   p += (size_t)NE*NT*4;
  int*   posm = (int*)p;   p += (size_t)NT*NE*4;
  int*   cnt  = (int*)p;   p += 64;
  f16* qwh  = (f16*)p; p += (size_t)C*N3C*2;             // per-layer weight splits
  f16* qwl  = (f16*)p; p += (size_t)C*N3C*2;
  f16* pwh  = (f16*)p; p += (size_t)C*C*2;
  f16* pwl  = (f16*)p; p += (size_t)C*C*2;
  f16* t1wh = (f16*)p; p += (size_t)C*TD*2;
  f16* t1wl = (f16*)p; p += (size_t)C*TD*2;
  f16* t2wh = (f16*)p; p += (size_t)TD*C*2;
  f16* t2wl = (f16*)p; p += (size_t)TD*C*2;
  f16* hwh  = (f16*)p; p += (size_t)C*NV*2;
  f16* hwl  = (f16*)p; p += (size_t)C*NV*2;
  f16* e1wh = (f16*)p; p += (size_t)NE*C*FF*2;
  f16* e1wl = (f16*)p; p += (size_t)NE*C*FF*2;
  f16* e2wh = (f16*)p; p += (size_t)NE*C*FF*2;
  f16* e2wl = (f16*)p; p += (size_t)NE*C*FF*2;

  dim3 b256(256);
  k_embed<<<dim3((NT*C+255)/256), b256, 0, stream>>>(tokens, tok_emb, pos_emb, x);
  k_wsplit<<<dim3(C/32, NV/32, 1), b256, 0, stream>>>(head_w, hwh, hwl, C, NV);
  for(int l=0;l<LAYERS;l++){
    k_ln<<<dim3(NT/4), b256, 0, stream>>>(x, ln1_w+l*C, ln1_b+l*C, h1h, h1l);
    k_wsplit<<<dim3(C/32, N3C/32, 1), b256, 0, stream>>>(
        qkv_w + (size_t)l*C*N3C, qwh, qwl, C, N3C);
    k_mfma<0,false,false><<<dim3(N3C/128, NT/128), b256, 0, stream>>>(
        h1h, h1l, qwh, qwl, qkv_b + (size_t)l*N3C,
        nullptr, nullptr, 0, 0, nullptr, nullptr, qkvb, C, C, C, N3C);
    k_attn<<<dim3(BB*NH), b256, 0, stream>>>(qkvb, mem, attn_g+(size_t)l*C, yh, yl);
    k_wsplit<<<dim3(C/32, C/32, 1), b256, 0, stream>>>(
        proj_w + (size_t)l*C*C, pwh, pwl, C, C);
    k_mfma<3,false,false><<<dim3(C/128, NT/128), b256, 0, stream>>>(
        yh, yl, pwh, pwl, proj_b + (size_t)l*C,
        nullptr, nullptr, 0, 0, pAh, pAl, x, C, C, C, C);
    k_wsplit<<<dim3(C/32, TD/32, 1), b256, 0, stream>>>(
        th1_w + (size_t)l*C*TD, t1wh, t1wl, C, TD);
    k_mfma<4,false,false><<<dim3(TD/128, NT/128), b256, 0, stream>>>(
        pAh, pAl, t1wh, t1wl, th1_b + (size_t)l*TD,
        nullptr, nullptr, 0, 0, t1h, t1l, nullptr, C, C, C, TD);
    k_wsplit<<<dim3(TD/32, C/32, 1), b256, 0, stream>>>(
        th2_w + (size_t)l*TD*C, t2wh, t2wl, TD, C);
    k_mfma<1,false,false><<<dim3(C/128, NT/128), b256, 0, stream>>>(
        t1h, t1l, t2wh, t2wl, th2_b + (size_t)l*C,
        nullptr, nullptr, 0, 0, nullptr, nullptr, x, TD, TD, TD, C);
    k_ln<<<dim3(NT/4), b256, 0, stream>>>(x, ln2_w+l*C, ln2_b+l*C, pAh, pAl);
    k_gate<<<dim3(NT/4), b256, 0, stream>>>(pAh, pAl,
        gate_w+(size_t)l*C*NE, gate_b+(size_t)l*NE, wbuf);
    k_compact<<<dim3(NE), b256, 0, stream>>>(wbuf, ridx, posm, cnt);
    k_wsplit<<<dim3(C/32, FF/32, NE), b256, 0, stream>>>(
        e1_w + (size_t)l*NE*C*FF, e1wh, e1wl, C, FF);
    k_wsplit<<<dim3(FF/32, C/32, NE), b256, 0, stream>>>(
        e2_w + (size_t)l*NE*FF*C, e2wh, e2wl, FF, C);
    for(int f0=0; f0<FF; f0+=FCH){
      // he = gelu(h2[sel] @ e1[:, f0:f0+FCH] + e1_b) -> f16 pair
      k_mfma<2,true,true><<<dim3(FCH/128, NT/128, NE), b256, 0, stream>>>(
          pAh, pAl, e1wh + (size_t)f0*C, e1wl + (size_t)f0*C,
          e1_b + (size_t)l*NE*FF + f0,
          ridx, cnt, (size_t)C*FF, (size_t)FF,
          heh, hel, nullptr, C, C, C, FCH);
      // ye (+)= he @ e2[f0:f0+FCH, :] (+ e2_b on first chunk)
      if (f0==0)
        k_mfma<0,true,false><<<dim3(C/128, NT/128, NE), b256, 0, stream>>>(
            heh, hel, e2wh + f0, e2wl + f0,
            e2_b + (size_t)l*NE*C,
            nullptr, cnt, (size_t)C*FF, (size_t)C,
            nullptr, nullptr, ye, FCH, FCH, FF, C);
      else
        k_mfma<1,true,false><<<dim3(C/128, NT/128, NE), b256, 0, stream>>>(
            heh, hel, e2wh + f0, e2wl + f0,
            nullptr,
            nullptr, cnt, (size_t)C*FF, (size_t)C,
            nullptr, nullptr, ye, FCH, FCH, FF, C);
    }
    k_moe_gather<<<dim3((NT*(C/4)+255)/256), b256, 0, stream>>>(ye, wbuf, posm, cnt, x);
  }
  k_ln<<<dim3(NT/4), b256, 0, stream>>>(x, lnf_w, lnf_b, pAh, pAl);
  k_mfma<0,false,false><<<dim3(NV/128, NT/128), b256, 0, stream>>>(
      pAh, pAl, hwh, hwl, head_b,
      nullptr, nullptr, 0, 0, nullptr, nullptr, out, C, C, C, NV);
}

// Round 16
// 9324.023 us; speedup vs baseline: 1.0113x; 1.0113x over previous
//
#include <hip/hip_runtime.h>
#include <math.h>

#define LAYERS 8
#define C 384
#define NH 8
#define NE 4
#define TD 256
#define NV 256
#define WIN 64
#define MM 56
#define HD 48
#define BB 64
#define TT 256
#define NT (BB*TT)
#define N3C 1152
#define FF 1536
#define KV 312
#define ACH 104              // attention KV chunk rows (3*104 = 312)
#define FCH 384              // MoE FF chunk width (768 overflowed rb — r14 crash)
#define SCALE_QK 0.14433756729740643f

typedef _Float16 f16;
typedef __attribute__((ext_vector_type(8))) _Float16 f16x8;
typedef __attribute__((ext_vector_type(4))) _Float16 f16x4;
typedef __attribute__((ext_vector_type(4))) float f32x4;

static __device__ __forceinline__ float wsum(float v){
#pragma unroll
  for(int o=32;o;o>>=1) v += __shfl_xor(v,o);
  return v;
}

// ---------------- embed ----------------
__global__ void k_embed(const int* __restrict__ tokens, const float* __restrict__ tok_emb,
                        const float* __restrict__ pos_emb, float* __restrict__ x){
  int idx = blockIdx.x*256 + threadIdx.x;
  if (idx >= NT*C) return;
  int t = idx / C, c = idx - t*C;
  x[idx] = tok_emb[tokens[t]*C + c] + pos_emb[(t % TT)*C + c];
}

// ---------------- layernorm -> f16 hi/lo pair (initial ln1 only) ----------------
__global__ void k_ln(const float* __restrict__ in, const float* __restrict__ w,
                     const float* __restrict__ b,
                     f16* __restrict__ oh, f16* __restrict__ ol){
  int row = blockIdx.x*4 + (threadIdx.x>>6);
  int lane = threadIdx.x & 63;
  const float* xr = in + (size_t)row*C;
  float v[6]; float s = 0.f;
#pragma unroll
  for(int i=0;i<6;i++){ v[i]=xr[lane+64*i]; s+=v[i]; }
  s = wsum(s);
  float mu = s*(1.f/C);
  float q=0.f;
#pragma unroll
  for(int i=0;i<6;i++){ float d=v[i]-mu; q+=d*d; }
  q = wsum(q);
  float inv = rsqrtf(q*(1.f/C)+1e-5f);
#pragma unroll
  for(int i=0;i<6;i++){
    int c = lane+64*i;
    float o = (v[i]-mu)*inv*w[c]+b[c];
    size_t oi = (size_t)row*C + c;
    f16 hh = (f16)o;
    oh[oi] = hh;
    ol[oi] = (f16)(o - (float)hh);
  }
}

// ---------------- fused ln2 + router gate ----------------
__global__ void k_ln2gate(const float* __restrict__ in, const float* __restrict__ w,
                          const float* __restrict__ b, const float* __restrict__ gw,
                          const float* __restrict__ gb,
                          f16* __restrict__ oh, f16* __restrict__ ol,
                          float* __restrict__ wout){
  int row = blockIdx.x*4 + (threadIdx.x>>6);
  int lane = threadIdx.x & 63;
  const float* xr = in + (size_t)row*C;
  float v[6]; float s = 0.f;
#pragma unroll
  for(int i=0;i<6;i++){ v[i]=xr[lane+64*i]; s+=v[i]; }
  s = wsum(s);
  float mu = s*(1.f/C);
  float q=0.f;
#pragma unroll
  for(int i=0;i<6;i++){ float d=v[i]-mu; q+=d*d; }
  q = wsum(q);
  float inv = rsqrtf(q*(1.f/C)+1e-5f);
  float a0=0,a1=0,a2=0,a3=0;
#pragma unroll
  for(int i=0;i<6;i++){
    int c = lane+64*i;
    float o = (v[i]-mu)*inv*w[c]+b[c];
    size_t oi = (size_t)row*C + c;
    f16 hh = (f16)o;
    oh[oi] = hh;
    ol[oi] = (f16)(o - (float)hh);
    const float* g = gw + (size_t)c*NE;
    a0 += o*g[0]; a1 += o*g[1]; a2 += o*g[2]; a3 += o*g[3];
  }
  a0=wsum(a0); a1=wsum(a1); a2=wsum(a2); a3=wsum(a3);
  if (lane==0){
    float p[4]={a0+gb[0],a1+gb[1],a2+gb[2],a3+gb[3]};
    float m = fmaxf(fmaxf(p[0],p[1]),fmaxf(p[2],p[3]));
    float ssum=0.f;
#pragma unroll
    for(int e=0;e<4;e++){ p[e]=expf(p[e]-m); ssum+=p[e]; }
#pragma unroll
    for(int e=0;e<4;e++) p[e] /= ssum;
    int i1=0;
    for(int e=1;e<4;e++) if(p[e]>p[i1]) i1=e;
    int i2=-1;
    for(int e=0;e<4;e++){ if(e==i1) continue; if(i2<0 || p[e]>p[i2]) i2=e; }
    float invs = 1.f/(p[i1]+p[i2]+1e-9f);
    float wv[4]={0.f,0.f,0.f,0.f};
    wv[i1]=p[i1]*invs; wv[i2]=p[i2]*invs;
    float* o = wout + (size_t)row*NE;
    o[0]=wv[0]; o[1]=wv[1]; o[2]=wv[2]; o[3]=wv[3];
  }
}

// ---------------- fused MoE gather + next-layer LN (-> pair) ----------------
// x[t] += sum_e w[t,e]*ye[eb[e]+pos]; then LN(x[t]) -> pair (next ln1 / lnf).
__global__ void k_gather_ln(const float* __restrict__ ye,
    const float* __restrict__ wbuf, const int* __restrict__ posm,
    const int* __restrict__ cnt, float* __restrict__ x,
    const float* __restrict__ lnw, const float* __restrict__ lnb,
    f16* __restrict__ oh, f16* __restrict__ ol){
  int row = blockIdx.x*4 + (threadIdx.x>>6);
  int lane = threadIdx.x & 63;
  int eb[NE]; int s0=0;
#pragma unroll
  for(int e=0;e<NE;e++){ eb[e]=s0; s0+=cnt[e]; }
  float* xr = x + (size_t)row*C;
  float v[6];
#pragma unroll
  for(int i=0;i<6;i++) v[i]=xr[lane+64*i];
#pragma unroll
  for(int e=0;e<NE;e++){
    int p = posm[(size_t)row*NE + e];
    if (p >= 0){
      float w = wbuf[(size_t)row*NE + e];
      const float* yr = ye + (size_t)(eb[e]+p)*C;
#pragma unroll
      for(int i=0;i<6;i++) v[i] += w*yr[lane+64*i];
    }
  }
#pragma unroll
  for(int i=0;i<6;i++) xr[lane+64*i]=v[i];
  float s = 0.f;
#pragma unroll
  for(int i=0;i<6;i++) s+=v[i];
  s = wsum(s);
  float mu = s*(1.f/C);
  float q=0.f;
#pragma unroll
  for(int i=0;i<6;i++){ float d=v[i]-mu; q+=d*d; }
  q = wsum(q);
  float inv = rsqrtf(q*(1.f/C)+1e-5f);
#pragma unroll
  for(int i=0;i<6;i++){
    int c = lane+64*i;
    float o = (v[i]-mu)*inv*lnw[c]+lnb[c];
    size_t oi = (size_t)row*C + c;
    f16 hh = (f16)o;
    oh[oi] = hh;
    ol[oi] = (f16)(o - (float)hh);
  }
}

// ---------------- weight split+transpose: W[K][N] fp32 -> WhT/WlT [N][K] f16 ----------------
__global__ __launch_bounds__(256) void k_wsplit(const float* __restrict__ W,
    f16* __restrict__ WhT, f16* __restrict__ WlT, int Kn, int Nn){
  __shared__ float s[32][33];
  const size_t ofs = (size_t)blockIdx.z*Kn*Nn;
  const float* Wb = W + ofs;
  f16* Th = WhT + ofs;
  f16* Tl = WlT + ofs;
  int k0 = (int)blockIdx.x<<5, n0 = (int)blockIdx.y<<5;
  int t = threadIdx.x;
  int r = t>>3, c4 = (t&7)<<2;
  float4 v = *(const float4*)(Wb + (size_t)(k0+r)*Nn + n0 + c4);
  s[r][c4+0]=v.x; s[r][c4+1]=v.y; s[r][c4+2]=v.z; s[r][c4+3]=v.w;
  __syncthreads();
  f16x4 hv, lv;
#pragma unroll
  for(int i=0;i<4;i++){
    float f = s[c4+i][r];
    f16 hh = (f16)f;
    hv[i] = hh;
    lv[i] = (f16)(f - (float)hh);
  }
  *(f16x4*)(Th + (size_t)(n0+r)*Kn + k0 + c4) = hv;
  *(f16x4*)(Tl + (size_t)(n0+r)*Kn + k0 + c4) = lv;
}

// ---------------- pair MFMA GEMM: fp16-split 3-pass, 128x128 tile, 4 waves ----------------
// D = A*B, A/B split hi+lo f16: acc += Ah*Bh + Ah*Bl + Al*Bh  (rel err ~2^-22).
// EPI 0: Of = val (+bias if bz)          (qkv, head, e2 first chunk)
// EPI 1: Of += val (+bias if bz)         (th2, e2 later chunks)
// EPI 2: gelu(val+bias) -> pair Oh/Ol    (e1)
// EPI 3: nv = Of+val+bias; Of=nv; pair(nv) -> Oh/Ol   (proj: x-accum + x-pair)
// EPI 4: tanh(val+bias) -> pair Oh/Ol    (th1)
// MOE: blockIdx.z = expert (cnt/eb); GATHER: A rows via ridx.
template<int EPI, bool MOE, bool GATHER>
__global__ __launch_bounds__(256) void k_mfma(
    const f16* __restrict__ Ah16, const f16* __restrict__ Al16,
    const f16* __restrict__ WhT, const f16* __restrict__ WlT,
    const float* __restrict__ bias,
    const int* __restrict__ ridx, const int* __restrict__ cnt,
    size_t sW, size_t sB,
    f16* __restrict__ Oh, f16* __restrict__ Ol, float* __restrict__ Of,
    int Kn, int ldA, int ldW, int ldC)
{
  const int z = MOE ? (int)blockIdx.z : 0;
  int Mn = NT, eb = 0;
  if (MOE){
    Mn = 0;
#pragma unroll
    for(int i=0;i<NE;i++){ int ci = cnt[i]; if (i<z) eb += ci; if (i==z) Mn = ci; }
  }
  const int bm = (int)blockIdx.y<<7, bn = (int)blockIdx.x<<7;
  if (bm >= Mn) return;
  const f16* Wh = WhT + (MOE ? (size_t)z*sW : 0);
  const f16* Wl = WlT + (MOE ? (size_t)z*sW : 0);
  const float* bz = bias ? (bias + (MOE ? (size_t)z*sB : 0)) : nullptr;

  __shared__ f16 AhS[128][40];
  __shared__ f16 AlS[128][40];
  __shared__ f16 BhS[128][40];
  __shared__ f16 BlS[128][40];

  const int tid = threadIdx.x;
  const int lane = tid & 63, wave = tid >> 6;
  const int srow = tid >> 1, sh2 = tid & 1;
  int r0 = bm + srow; if (r0 >= Mn) r0 = Mn - 1;
  const int agr = GATHER ? ridx[(size_t)z*NT + r0] : (eb + r0);
  const f16* As_h = Ah16 + (size_t)agr*ldA + (sh2<<4);
  const f16* As_l = Al16 + (size_t)agr*ldA + (sh2<<4);
  const f16* Bs_h = Wh + (size_t)(bn + srow)*ldW + (sh2<<4);
  const f16* Bs_l = Wl + (size_t)(bn + srow)*ldW + (sh2<<4);

  const int wr = (wave>>1)<<6, wc = (wave&1)<<6;
  const int l15 = lane & 15, koff = (lane>>4)<<3;
  f32x4 acc[4][4] = {};
  const int T = Kn >> 5;
  for (int t=0; t<T; t++){
    const int k0 = t<<5;
    __syncthreads();                       // WAR: previous frag reads complete
    {
      f16x8 a0 = *(const f16x8*)(As_h + k0);
      f16x8 a1 = *(const f16x8*)(As_h + k0 + 8);
      f16x8 a2 = *(const f16x8*)(As_l + k0);
      f16x8 a3 = *(const f16x8*)(As_l + k0 + 8);
      f16x8 b0 = *(const f16x8*)(Bs_h + k0);
      f16x8 b1 = *(const f16x8*)(Bs_h + k0 + 8);
      f16x8 b2 = *(const f16x8*)(Bs_l + k0);
      f16x8 b3 = *(const f16x8*)(Bs_l + k0 + 8);
      *(f16x8*)&AhS[srow][sh2<<4]     = a0;
      *(f16x8*)&AhS[srow][(sh2<<4)+8] = a1;
      *(f16x8*)&AlS[srow][sh2<<4]     = a2;
      *(f16x8*)&AlS[srow][(sh2<<4)+8] = a3;
      *(f16x8*)&BhS[srow][sh2<<4]     = b0;
      *(f16x8*)&BhS[srow][(sh2<<4)+8] = b1;
      *(f16x8*)&BlS[srow][sh2<<4]     = b2;
      *(f16x8*)&BlS[srow][(sh2<<4)+8] = b3;
    }
    __syncthreads();                       // staged tile visible
    f16x8 fah[4], fal[4], fbh[4], fbl[4];
#pragma unroll
    for(int m=0;m<4;m++){
      fah[m] = *(const f16x8*)&AhS[wr + (m<<4) + l15][koff];
      fal[m] = *(const f16x8*)&AlS[wr + (m<<4) + l15][koff];
    }
#pragma unroll
    for(int n=0;n<4;n++){
      fbh[n] = *(const f16x8*)&BhS[wc + (n<<4) + l15][koff];
      fbl[n] = *(const f16x8*)&BlS[wc + (n<<4) + l15][koff];
    }
#pragma unroll
    for(int m=0;m<4;m++)
#pragma unroll
      for(int n=0;n<4;n++){
        acc[m][n] = __builtin_amdgcn_mfma_f32_16x16x32_f16(fah[m], fbh[n], acc[m][n], 0,0,0);
        acc[m][n] = __builtin_amdgcn_mfma_f32_16x16x32_f16(fah[m], fbl[n], acc[m][n], 0,0,0);
        acc[m][n] = __builtin_amdgcn_mfma_f32_16x16x32_f16(fal[m], fbh[n], acc[m][n], 0,0,0);
      }
  }
  // epilogue: C/D layout col=lane&15, row=(lane>>4)*4+reg
  const int r4 = (lane>>4)<<2;
#pragma unroll
  for(int m=0;m<4;m++){
#pragma unroll
    for(int n=0;n<4;n++){
      const int col = bn + wc + (n<<4) + l15;
#pragma unroll
      for(int rr=0;rr<4;rr++){
        const int row = bm + wr + (m<<4) + r4 + rr;
        if (row < Mn){
          float val = acc[m][n][rr];
          const size_t o = (size_t)(eb+row)*ldC + col;
          if (EPI==2 || EPI==4){
            val += bz[col];
            val = (EPI==2) ? 0.5f*val*(1.0f+erff(val*0.70710678118654752f)) : tanhf(val);
            f16 hv = (f16)val;
            Oh[o] = hv;
            Ol[o] = (f16)(val - (float)hv);
          } else if (EPI==3){
            val += bz[col];
            float nv = Of[o] + val;
            Of[o] = nv;
            f16 hv = (f16)nv;
            Oh[o] = hv;
            Ol[o] = (f16)(nv - (float)hv);
          } else if (EPI==1){
            if (bz) val += bz[col];
            Of[o] += val;
          } else {
            if (bz) val += bz[col];
            Of[o] = val;
          }
        }
      }
    }
  }
}

// ---------------- attention: chunked flash, lane-per-query, y -> f16 pair ----------------
__global__ __launch_bounds__(256) void k_attn(const float* __restrict__ qkv,
    const float* __restrict__ mem, const float* __restrict__ gate,
    f16* __restrict__ yh, f16* __restrict__ yl){
  __shared__ float ks[ACH*50];
  __shared__ float vs[ACH*50];
  const int b = blockIdx.x >> 3, hh = blockIdx.x & 7;
  const int tid = threadIdx.x;
  const int i = tid;
  const float* qrow = qkv + (size_t)(b*TT+i)*N3C + hh*HD;
  float q[HD];
#pragma unroll
  for(int d2=0; d2<24; d2++){
    float2 qv = *(const float2*)(qrow + d2*2);
    q[d2*2] = qv.x; q[d2*2+1] = qv.y;
  }
  float m = -1e30f, l = 0.f;
  float acc[HD];
#pragma unroll
  for(int d=0;d<HD;d++) acc[d]=0.f;
  const int lo = (i > WIN) ? (i - WIN) : 0;

#define ATT_STEP(JROW) {                                            \
    const float* kr = ks + (JROW)*50;                               \
    float dot = 0.f;                                                \
    _Pragma("unroll")                                               \
    for(int d2=0; d2<24; d2++){                                     \
      float2 kv2 = *(const float2*)(kr + d2*2);                     \
      dot += q[d2*2]*kv2.x + q[d2*2+1]*kv2.y;                       \
    }                                                               \
    float s = dot*SCALE_QK;                                         \
    if (s > m + 8.f){                                               \
      float f_ = __expf(m - s);                                     \
      l *= f_;                                                      \
      _Pragma("unroll")                                             \
      for(int d=0; d<HD; d++) acc[d] *= f_;                         \
      m = s;                                                        \
    }                                                               \
    float pch = __expf(s - m);                                      \
    l += pch;                                                       \
    const float* vr = vs + (JROW)*50;                               \
    _Pragma("unroll")                                               \
    for(int d2=0; d2<24; d2++){                                     \
      float2 vv2 = *(const float2*)(vr + d2*2);                     \
      acc[d2*2]   += pch*vv2.x;                                     \
      acc[d2*2+1] += pch*vv2.y;                                     \
    }                                                               \
  }

  for (int ch=0; ch<3; ++ch){
    const int j0 = ch*ACH;
    if (ch) __syncthreads();             // WAR before restaging
    for(int idx=tid; idx<ACH*24; idx+=256){
      int jr = idx/24, f = (idx - jr*24)*2;
      int j = j0 + jr;
      float2 kvv, vvv;
      if (j < MM){
        kvv = *(const float2*)(mem + j*C + hh*HD + f);
        vvv = kvv;
      } else {
        const float* row = qkv + (size_t)(b*TT + j - MM)*N3C + hh*HD + f;
        kvv = *(const float2*)(row + C);
        vvv = *(const float2*)(row + 2*C);
      }
      *(float2*)(ks + jr*50 + f) = kvv;
      *(float2*)(vs + jr*50 + f) = vvv;
    }
    __syncthreads();
    const int mend = (MM < j0+ACH) ? MM : (j0+ACH);
    for (int j=j0; j<mend; ++j) ATT_STEP(j-j0)
    const int slo = (MM+lo > j0) ? (MM+lo) : j0;
    const int shi = (MM+i+1 < j0+ACH) ? (MM+i+1) : (j0+ACH);
    for (int j=slo; j<shi; ++j) ATT_STEP(j-j0)
  }
#undef ATT_STEP

  const float inv = 1.f/l;
  const float* g = gate + hh*HD;
  const size_t base = (size_t)(b*TT+i)*C + hh*HD;
#pragma unroll
  for(int d=0;d<HD;d++){
    float o = acc[d]*inv*g[d];
    f16 hv = (f16)o;
    yh[base+d] = hv;
    yl[base+d] = (f16)(o - (float)hv);
  }
}

// ---------------- per-expert compaction + inverse map ----------------
__global__ __launch_bounds__(256) void k_compact(const float* __restrict__ wbuf,
    int* __restrict__ ridx, int* __restrict__ posmap, int* __restrict__ cnt){
  int e = blockIdx.x;
  int tid = threadIdx.x;
  int wave = tid>>6, lane = tid&63;
  __shared__ int wsum_s[4];
  __shared__ int base_s;
  if (tid==0) base_s = 0;
  __syncthreads();
  for(int t0=0; t0<NT; t0+=256){
    int t = t0 + tid;
    bool f = wbuf[(size_t)t*NE + e] > 0.f;
    unsigned long long bal = __ballot(f);
    int pre = __popcll(bal & ((1ull<<lane)-1ull));
    if (lane==0) wsum_s[wave] = __popcll(bal);
    __syncthreads();
    int off = 0;
#pragma unroll
    for(int w2=0;w2<4;w2++) if (w2 < wave) off += wsum_s[w2];
    int tot = wsum_s[0]+wsum_s[1]+wsum_s[2]+wsum_s[3];
    int b0 = base_s;
    int pos = b0 + off + pre;
    if (f) ridx[(size_t)e*NT + pos] = t;
    posmap[(size_t)t*NE + e] = f ? pos : -1;
    __syncthreads();
    if (tid==0) base_s = b0 + tot;
    __syncthreads();
  }
  if (tid==0) cnt[e] = base_s;
}

extern "C" void kernel_launch(void* const* d_in, const int* in_sizes, int n_in,
                              void* d_out, int out_size, void* d_ws, size_t ws_size,
                              hipStream_t stream){
  (void)in_sizes; (void)n_in; (void)out_size; (void)ws_size;
  const int*   tokens  = (const int*)d_in[0];
  const float* tok_emb = (const float*)d_in[1];
  const float* pos_emb = (const float*)d_in[2];
  const float* mem     = (const float*)d_in[3];
  const float* ln1_w   = (const float*)d_in[4];
  const float* ln1_b   = (const float*)d_in[5];
  const float* qkv_w   = (const float*)d_in[6];
  const float* qkv_b   = (const float*)d_in[7];
  const float* proj_w  = (const float*)d_in[8];
  const float* proj_b  = (const float*)d_in[9];
  const float* attn_g  = (const float*)d_in[10];
  const float* th1_w   = (const float*)d_in[11];
  const float* th1_b   = (const float*)d_in[12];
  const float* th2_w   = (const float*)d_in[13];
  const float* th2_b   = (const float*)d_in[14];
  const float* ln2_w   = (const float*)d_in[15];
  const float* ln2_b   = (const float*)d_in[16];
  const float* gate_w  = (const float*)d_in[17];
  const float* gate_b  = (const float*)d_in[18];
  const float* e1_w    = (const float*)d_in[19];
  const float* e1_b    = (const float*)d_in[20];
  const float* e2_w    = (const float*)d_in[21];
  const float* e2_b    = (const float*)d_in[22];
  const float* lnf_w   = (const float*)d_in[23];
  const float* lnf_b   = (const float*)d_in[24];
  const float* head_w  = (const float*)d_in[25];
  const float* head_b  = (const float*)d_in[26];
  float* out = (float*)d_out;

  char* p = (char*)d_ws;
  float* x   = (float*)p; p += (size_t)NT*C*4;          // residual fp32
  f16* pAh = (f16*)p;                                    // pair plane: h1p -> xp -> h2p -> next h1p / lnf
  f16* pAl = pAh + (size_t)NT*C;
  p += (size_t)NT*C*4;
  char* rb = p; p += (size_t)NT*N3C*4 + (size_t)2*NT*TD*4;   // 109.05 MB region
  float* qkvb = (float*)rb;                              // [0, 75.5MB)
  char* shreg = rb + (size_t)NT*N3C*4;                   // [75.5, 109MB)
  f16* yh  = (f16*)shreg; f16* yl = yh + (size_t)NT*C;   // attn pair (dead after proj)
  f16* t1h = (f16*)shreg; f16* t1l = t1h + (size_t)NT*TD;// th1 pair (dead after th2)
  // MoE-phase aliases in rb (qkvb + shreg dead then). FCH=384:
  // heh [0,25.17), hel [25.17,50.33), ye [50.33,100.66) MB — fits 109.05.
  f16* heh = (f16*)rb;
  f16* hel = heh + (size_t)2*NT*FCH;
  float* ye = (float*)(rb + (size_t)2*2*NT*FCH*2);
  float* wbuf = (float*)p; p += (size_t)NT*NE*4;
  int*   ridx = (int*)p;   p += (size_t)NE*NT*4;
  int*   posm = (int*)p;   p += (size_t)NT*NE*4;
  int*   cnt  = (int*)p;   p += 64;
  // all-layer small-weight splits (hoisted; +25.5MB)
  f16* qwh  = (f16*)p; p += (size_t)LAYERS*C*N3C*2;
  f16* qwl  = (f16*)p; p += (size_t)LAYERS*C*N3C*2;
  f16* pwh  = (f16*)p; p += (size_t)LAYERS*C*C*2;
  f16* pwl  = (f16*)p; p += (size_t)LAYERS*C*C*2;
  f16* t1wh = (f16*)p; p += (size_t)LAYERS*C*TD*2;
  f16* t1wl = (f16*)p; p += (size_t)LAYERS*C*TD*2;
  f16* t2wh = (f16*)p; p += (size_t)LAYERS*TD*C*2;
  f16* t2wl = (f16*)p; p += (size_t)LAYERS*TD*C*2;
  f16* hwh  = (f16*)p; p += (size_t)C*NV*2;
  f16* hwl  = (f16*)p; p += (size_t)C*NV*2;
  // per-layer rotating expert splits (18.9MB)
  f16* e1wh = (f16*)p; p += (size_t)NE*C*FF*2;
  f16* e1wl = (f16*)p; p += (size_t)NE*C*FF*2;
  f16* e2wh = (f16*)p; p += (size_t)NE*C*FF*2;
  f16* e2wl = (f16*)p; p += (size_t)NE*C*FF*2;

  dim3 b256(256);
  k_embed<<<dim3((NT*C+255)/256), b256, 0, stream>>>(tokens, tok_emb, pos_emb, x);
  // hoisted all-layer weight splits
  k_wsplit<<<dim3(C/32, N3C/32, LAYERS), b256, 0, stream>>>(qkv_w,  qwh,  qwl,  C,  N3C);
  k_wsplit<<<dim3(C/32, C/32,   LAYERS), b256, 0, stream>>>(proj_w, pwh,  pwl,  C,  C);
  k_wsplit<<<dim3(C/32, TD/32,  LAYERS), b256, 0, stream>>>(th1_w,  t1wh, t1wl, C,  TD);
  k_wsplit<<<dim3(TD/32, C/32,  LAYERS), b256, 0, stream>>>(th2_w,  t2wh, t2wl, TD, C);
  k_wsplit<<<dim3(C/32, NV/32,  1),      b256, 0, stream>>>(head_w, hwh,  hwl,  C,  NV);
  k_ln<<<dim3(NT/4), b256, 0, stream>>>(x, ln1_w, ln1_b, pAh, pAl);
  for(int l=0;l<LAYERS;l++){
    k_mfma<0,false,false><<<dim3(N3C/128, NT/128), b256, 0, stream>>>(
        pAh, pAl, qwh + (size_t)l*C*N3C, qwl + (size_t)l*C*N3C, qkv_b + (size_t)l*N3C,
        nullptr, nullptr, 0, 0, nullptr, nullptr, qkvb, C, C, C, N3C);
    k_attn<<<dim3(BB*NH), b256, 0, stream>>>(qkvb, mem, attn_g+(size_t)l*C, yh, yl);
    k_mfma<3,false,false><<<dim3(C/128, NT/128), b256, 0, stream>>>(
        yh, yl, pwh + (size_t)l*C*C, pwl + (size_t)l*C*C, proj_b + (size_t)l*C,
        nullptr, nullptr, 0, 0, pAh, pAl, x, C, C, C, C);
    k_mfma<4,false,false><<<dim3(TD/128, NT/128), b256, 0, stream>>>(
        pAh, pAl, t1wh + (size_t)l*C*TD, t1wl + (size_t)l*C*TD, th1_b + (size_t)l*TD,
        nullptr, nullptr, 0, 0, t1h, t1l, nullptr, C, C, C, TD);
    k_mfma<1,false,false><<<dim3(C/128, NT/128), b256, 0, stream>>>(
        t1h, t1l, t2wh + (size_t)l*TD*C, t2wl + (size_t)l*TD*C, th2_b + (size_t)l*C,
        nullptr, nullptr, 0, 0, nullptr, nullptr, x, TD, TD, TD, C);
    k_ln2gate<<<dim3(NT/4), b256, 0, stream>>>(x, ln2_w+l*C, ln2_b+l*C,
        gate_w+(size_t)l*C*NE, gate_b+(size_t)l*NE, pAh, pAl, wbuf);
    k_compact<<<dim3(NE), b256, 0, stream>>>(wbuf, ridx, posm, cnt);
    k_wsplit<<<dim3(C/32, FF/32, NE), b256, 0, stream>>>(
        e1_w + (size_t)l*NE*C*FF, e1wh, e1wl, C, FF);
    k_wsplit<<<dim3(FF/32, C/32, NE), b256, 0, stream>>>(
        e2_w + (size_t)l*NE*FF*C, e2wh, e2wl, FF, C);
    for(int f0=0; f0<FF; f0+=FCH){
      // he = gelu(h2[sel] @ e1[:, f0:f0+FCH] + e1_b) -> f16 pair
      k_mfma<2,true,true><<<dim3(FCH/128, NT/128, NE), b256, 0, stream>>>(
          pAh, pAl, e1wh + (size_t)f0*C, e1wl + (size_t)f0*C,
          e1_b + (size_t)l*NE*FF + f0,
          ridx, cnt, (size_t)C*FF, (size_t)FF,
          heh, hel, nullptr, C, C, C, FCH);
      // ye (+)= he @ e2[f0:f0+FCH, :] (+ e2_b on first chunk)
      if (f0==0)
        k_mfma<0,true,false><<<dim3(C/128, NT/128, NE), b256, 0, stream>>>(
            heh, hel, e2wh + f0, e2wl + f0,
            e2_b + (size_t)l*NE*C,
            nullptr, cnt, (size_t)C*FF, (size_t)C,
            nullptr, nullptr, ye, FCH, FCH, FF, C);
      else
        k_mfma<1,true,false><<<dim3(C/128, NT/128, NE), b256, 0, stream>>>(
            heh, hel, e2wh + f0, e2wl + f0,
            nullptr,
            nullptr, cnt, (size_t)C*FF, (size_t)C,
            nullptr, nullptr, ye, FCH, FCH, FF, C);
    }
    // gather + (next ln1 | lnf) -> pair into pA
    const float* nlw = (l < LAYERS-1) ? (ln1_w + (size_t)(l+1)*C) : lnf_w;
    const float* nlb = (l < LAYERS-1) ? (ln1_b + (size_t)(l+1)*C) : lnf_b;
    k_gather_ln<<<dim3(NT/4), b256, 0, stream>>>(ye, wbuf, posm, cnt, x, nlw, nlb, pAh, pAl);
  }
  k_mfma<0,false,false><<<dim3(NV/128, NT/128), b256, 0, stream>>>(
      pAh, pAl, hwh, hwl, head_b,
      nullptr, nullptr, 0, 0, nullptr, nullptr, out, C, C, C, NV);
}